// Round 4
// baseline (300.468 us; speedup 1.0000x reference)
//
#include <hip/hip_runtime.h>
#include <stdint.h>

// ---------------------------------------------------------------------------
// MHA block, round 4.
// Theory r3: all kernels were LDS-staging-volume bound (L3 service ~5.6TB/s):
// qkv staged 384MB, attn 540MB, o_gemm 192MB for ~60MB of unique data.
// Changes:
//  * attn: 128-q blocks, wave owns 32 q (K/V-frag reads amortized 2x),
//    KT=128, paired q-blocks (z,15-z) -> 256 blocks x 256thr, uniform 17
//    iters; staging 540->139MB; Q/P wave-private (no barriers for them);
//    XCD swizzle keeps each XCD's 4 (b,h) K+V (2MB) L2-resident.
//  * qkv: y=L%8 XCD swizzle -> B-slabs (256KB each) become L2-local re-reads.
//  * o_gemm: 128x128 tile (staging 192->128MB) + same swizzle.
// ---------------------------------------------------------------------------

typedef unsigned short ushort_t;
typedef __attribute__((ext_vector_type(8))) __bf16 bf16x8;   // MFMA A/B operand
typedef __attribute__((ext_vector_type(4))) float floatx4;   // MFMA C/D operand

#define EMBED 1024
#define SEQ   2048
#define NH    16
#define DH    64
#define QK_SCALE 0.18033688011112042f   // 0.125 * log2(e)

// fp32 -> bf16 round-to-nearest-even (finite inputs)
__device__ inline ushort_t f2b(float x) {
  unsigned u = __float_as_uint(x);
  u += 0x7FFFu + ((u >> 16) & 1u);
  return (ushort_t)(u >> 16);
}

// pack bf16(a) | bf16(b)<<16 with +0x8000 round: 2 add + 1 perm
__device__ inline unsigned pk2(float a, float b) {
  unsigned ua = __float_as_uint(a) + 0x8000u;
  unsigned ub = __float_as_uint(b) + 0x8000u;
  return __builtin_amdgcn_perm(ub, ua, 0x07060302u);   // [a2,a3,b2,b3]
}

// async global->LDS, 16B/lane; LDS dest = wave-uniform base (+ lane*16 by HW)
__device__ inline void gl_lds16(const ushort_t* g, ushort_t* l) {
  __builtin_amdgcn_global_load_lds(
      (const __attribute__((address_space(1))) unsigned int*)g,
      (__attribute__((address_space(3))) unsigned int*)l, 16, 0, 0);
}

// ---------------------------------------------------------------------------
// fp32 -> bf16 bulk convert, with per-chunk scale (folds QK scale into Wq)
// ---------------------------------------------------------------------------
struct CvtArgs {
  const float* src[16];
  ushort_t*    dst[16];
  float        scale[16];
};

__global__ __launch_bounds__(256) void cvt_kernel(CvtArgs a) {
  const int chunk = blockIdx.x >> 9;
  const int off = ((blockIdx.x & 511) << 11) + (threadIdx.x << 3);
  const float sc = a.scale[chunk];
  const float4* s = (const float4*)(a.src[chunk] + off);
  float4 f0 = s[0], f1 = s[1];
  union { ushort_t u[8]; uint4 v; } o;
  o.u[0] = f2b(f0.x * sc); o.u[1] = f2b(f0.y * sc);
  o.u[2] = f2b(f0.z * sc); o.u[3] = f2b(f0.w * sc);
  o.u[4] = f2b(f1.x * sc); o.u[5] = f2b(f1.y * sc);
  o.u[6] = f2b(f1.z * sc); o.u[7] = f2b(f1.w * sc);
  *(uint4*)(a.dst[chunk] + off) = o.v;
}

// ---------------------------------------------------------------------------
// C[m,n] = sum_k A[m,k] * W[n,k].  128 x (NSUB*32) tile, BK=64, 4 waves 2x2,
// fragment-ordered LDS + global_load_lds.  Epilogue modes:
//   0 = bf16 row-major, 1 = f32 row-major, 2 = bf16 into VpT[b][h][d][s]
// ---------------------------------------------------------------------------
template <int NSUB>
__device__ inline void gemm_core(const ushort_t* __restrict__ A,
                                 const ushort_t* __restrict__ W,
                                 char* __restrict__ Cv, const int mode,
                                 const int K, const int ldc,
                                 const int m0, const int n0) {
  __shared__ ushort_t As[16 * 512];          // 128 x 64, fragment-ordered
  __shared__ ushort_t Bs[NSUB * 4 * 512];    // (NSUB*32) x 64
  const int tid  = threadIdx.x;
  const int lane = tid & 63;
  const int wid  = tid >> 6;
  const int lm   = lane & 15;
  const int quad = lane >> 4;

  int grow[4], gcol[4];
#pragma unroll
  for (int i = 0; i < 4; ++i) {
    const int c = wid + 4 * i;
    grow[i] = (c >> 1) * 16 + lm;
    gcol[i] = (c & 1) * 32 + quad * 8;
  }

  floatx4 zero = {0.f, 0.f, 0.f, 0.f};
  floatx4 acc[4][NSUB];
#pragma unroll
  for (int i = 0; i < 4; ++i)
#pragma unroll
    for (int j = 0; j < NSUB; ++j) acc[i][j] = zero;

  const int tm = (wid >> 1) * 4;
  const int tn = (wid & 1) * NSUB;

  for (int k0 = 0; k0 < K; k0 += 64) {
    __syncthreads();
#pragma unroll
    for (int i = 0; i < 4; ++i)
      gl_lds16(A + (size_t)(m0 + grow[i]) * K + k0 + gcol[i], &As[(wid + 4 * i) * 512]);
#pragma unroll
    for (int i = 0; i < NSUB; ++i)
      gl_lds16(W + (size_t)(n0 + grow[i]) * K + k0 + gcol[i], &Bs[(wid + 4 * i) * 512]);
    __syncthreads();   // vmcnt drain -> LDS visible

#pragma unroll
    for (int ks = 0; ks < 2; ++ks) {
      bf16x8 a[4], b[NSUB];
#pragma unroll
      for (int i = 0; i < 4; ++i)
        a[i] = *(const bf16x8*)&As[((tm + i) * 2 + ks) * 512 + lane * 8];
#pragma unroll
      for (int j = 0; j < NSUB; ++j)
        b[j] = *(const bf16x8*)&Bs[((tn + j) * 2 + ks) * 512 + lane * 8];
#pragma unroll
      for (int i = 0; i < 4; ++i)
#pragma unroll
        for (int j = 0; j < NSUB; ++j)
          acc[i][j] = __builtin_amdgcn_mfma_f32_16x16x32_bf16(a[i], b[j], acc[i][j], 0, 0, 0);
    }
  }

#pragma unroll
  for (int i = 0; i < 4; ++i) {
    const int row = m0 + (wid >> 1) * 64 + i * 16 + quad * 4;
#pragma unroll
    for (int j = 0; j < NSUB; ++j) {
      const int col = n0 + (wid & 1) * (NSUB * 16) + j * 16 + lm;
      if (mode == 0) {
        ushort_t* C = (ushort_t*)Cv;
#pragma unroll
        for (int r = 0; r < 4; ++r)
          C[(size_t)(row + r) * ldc + col] = f2b(acc[i][j][r]);
      } else if (mode == 1) {
        float* C = (float*)Cv;
#pragma unroll
        for (int r = 0; r < 4; ++r)
          C[(size_t)(row + r) * ldc + col] = acc[i][j][r];
      } else {
        // VpT[b][h][d][s]: r -> consecutive s, one 8B store
        ushort_t* C = (ushort_t*)Cv;
        const int b = row >> 11, s = row & 2047;
        const int h = col >> 6, d = col & 63;
        union { ushort_t u[4]; uint2 v; } pk;
#pragma unroll
        for (int r = 0; r < 4; ++r) pk.u[r] = f2b(acc[i][j][r]);
        *(uint2*)&C[(size_t)((b * NH + h) * DH + d) * SEQ + s] = pk.v;
      }
    }
  }
}

struct QkvArgs {
  const ushort_t* A[3];
  const ushort_t* W[3];
  char*           C[3];
};

// 1-D grid 768: y=L%8 (XCD-local B-slab), x=(L>>3)%32, z=(L>>3)/32
__global__ __launch_bounds__(256) void qkv_gemm(QkvArgs q) {
  const int L = blockIdx.x;
  const int y = L & 7, t = L >> 3;
  const int x = t & 31, z = t >> 5;
  gemm_core<4>(q.A[z], q.W[z], q.C[z], z == 2 ? 2 : 0, EMBED, EMBED,
               x * 128, y * 128);
}

// 1-D grid 256: y=L%8, x=L>>3
__global__ __launch_bounds__(256) void o_gemm(const ushort_t* __restrict__ A,
                                              const ushort_t* __restrict__ W,
                                              float* __restrict__ C) {
  const int L = blockIdx.x;
  gemm_core<4>(A, W, (char*)C, 1, EMBED, EMBED, (L >> 3) * 128, (L & 7) * 128);
}

// ---------------------------------------------------------------------------
// Causal flash attention, S^T formulation, fixed-shift softmax.
// Grid 256 x 256thr (4 waves).  Block = 128 q-cols (wave owns 32 = 2 q-groups),
// KT=128 kk per iter, q-block pair (z, 15-z) -> uniform 17 iters.
// XCD swizzle: 4 (b,h) per XCD -> K+V (2MB) L2-resident.
// Qs/Pw are wave-private (no barriers); Ks/VTs shared (2 barriers/iter).
// ---------------------------------------------------------------------------
__global__ __launch_bounds__(256) void attn_kernel(const ushort_t* __restrict__ Qp,
                                                   const ushort_t* __restrict__ Kp,
                                                   const ushort_t* __restrict__ VpT,
                                                   ushort_t* __restrict__ Ob) {
  __shared__ ushort_t Qs[16 * 512];    // 128 q x 64 d, fragment-ordered
  __shared__ ushort_t Ks[16 * 512];    // 128 kk x 64 d
  __shared__ ushort_t VTs[16 * 512];   // 64 d x 128 kk
  __shared__ ushort_t Pw[4 * 4096];    // per-wave 32 q x 128 kk
  const int L = blockIdx.x;            // 0..255
  const int xcd = L & 7, t = L >> 3;
  const int z = t & 7;                 // pair slot 0..7
  const int bh = (t >> 3) * 8 + xcd;   // 0..31, grouped per XCD
  const int h = bh & (NH - 1), b = bh >> 4;
  const int tid = threadIdx.x, lane = tid & 63, wid = tid >> 6;
  const int lm = lane & 15, quad = lane >> 4;
  const size_t qkbase = ((size_t)b * SEQ) * EMBED + h * DH;
  const size_t vtbase = ((size_t)(b * NH + h)) * DH * SEQ;
  ushort_t* pwb = &Pw[wid * 4096];

  for (int phase = 0; phase < 2; ++phase) {
    const int qb = phase ? (15 - z) : z;

    // Q staging: chunks c = wid*4+u are wave-private (qsub = c>>1 = wid*2+..)
#pragma unroll
    for (int u = 0; u < 4; ++u) {
      const int c = wid * 4 + u;
      gl_lds16(Qp + qkbase + (size_t)(qb * 128 + (c >> 1) * 16 + lm) * EMBED
                   + (c & 1) * 32 + quad * 8,
               &Qs[c * 512]);
    }
    asm volatile("s_waitcnt vmcnt(0)" ::: "memory");   // wave-local drain
    bf16x8 qf[2][2];   // [qg][ks]
#pragma unroll
    for (int qg = 0; qg < 2; ++qg)
#pragma unroll
      for (int ks = 0; ks < 2; ++ks)
        qf[qg][ks] = *(const bf16x8*)&Qs[((wid * 2 + qg) * 2 + ks) * 512 + lane * 8];

    float l_part[2] = {0.f, 0.f};
    floatx4 zero = {0.f, 0.f, 0.f, 0.f};
    floatx4 o_acc[4][2];
#pragma unroll
    for (int d = 0; d < 4; ++d)
#pragma unroll
      for (int qg = 0; qg < 2; ++qg) o_acc[d][qg] = zero;

    for (int kt = 0; kt <= qb; ++kt) {
      __syncthreads();   // prior iter's Ks/VTs reads done
#pragma unroll
      for (int u = 0; u < 4; ++u) {
        const int c = wid * 4 + u;
        gl_lds16(Kp + qkbase + (size_t)(kt * 128 + (c >> 1) * 16 + lm) * EMBED
                     + (c & 1) * 32 + quad * 8,
                 &Ks[c * 512]);
        gl_lds16(VpT + vtbase + (size_t)((c >> 2) * 16 + lm) * SEQ
                     + kt * 128 + (c & 3) * 32 + quad * 8,
                 &VTs[c * 512]);
      }
      __syncthreads();   // vmcnt drain -> LDS visible

      // S^T = K Q^T (log2e domain): s_acc[i][qg], i = kk-subtile 0..7
      floatx4 s_acc[8][2];
#pragma unroll
      for (int i = 0; i < 8; ++i)
#pragma unroll
        for (int qg = 0; qg < 2; ++qg) s_acc[i][qg] = zero;
#pragma unroll
      for (int ks = 0; ks < 2; ++ks)
#pragma unroll
        for (int i = 0; i < 8; ++i) {
          bf16x8 kf = *(const bf16x8*)&Ks[(i * 2 + ks) * 512 + lane * 8];
#pragma unroll
          for (int qg = 0; qg < 2; ++qg)
            s_acc[i][qg] = __builtin_amdgcn_mfma_f32_16x16x32_bf16(kf, qf[qg][ks], s_acc[i][qg], 0, 0, 0);
        }

      // exp2, diagonal mask, l accumulate, pack P^T into wave-private Pw
      const bool diag = (kt == qb);
#pragma unroll
      for (int i = 0; i < 8; ++i) {
        const int s = i >> 1;
        const int quadB = ((i & 1) << 1) | (quad >> 1);
        const int kkl = i * 16 + quad * 4;
#pragma unroll
        for (int qg = 0; qg < 2; ++qg) {
          float p[4];
#pragma unroll
          for (int r = 0; r < 4; ++r) p[r] = __builtin_amdgcn_exp2f(s_acc[i][qg][r]);
          if (diag) {
            const int ql = wid * 32 + qg * 16 + lm;
#pragma unroll
            for (int r = 0; r < 4; ++r)
              if (kkl + r > ql) p[r] = 0.f;
          }
#pragma unroll
          for (int r = 0; r < 4; ++r) l_part[qg] += p[r];
          uint2 pk;
          pk.x = pk2(p[0], p[1]);
          pk.y = pk2(p[2], p[3]);
          *(uint2*)&pwb[(qg * 4 + s) * 512 + (quadB * 16 + lm) * 8 + ((quad & 1) << 2)] = pk;
        }
      }
      asm volatile("s_waitcnt lgkmcnt(0)" ::: "memory");   // wave-local RAW fence

      // O^T += V^T P^T
#pragma unroll
      for (int s = 0; s < 4; ++s) {
        bf16x8 pf[2];
#pragma unroll
        for (int qg = 0; qg < 2; ++qg)
          pf[qg] = *(const bf16x8*)&pwb[(qg * 4 + s) * 512 + lane * 8];
#pragma unroll
        for (int d = 0; d < 4; ++d) {
          bf16x8 vf = *(const bf16x8*)&VTs[(d * 4 + s) * 512 + lane * 8];
#pragma unroll
          for (int qg = 0; qg < 2; ++qg)
            o_acc[d][qg] = __builtin_amdgcn_mfma_f32_16x16x32_bf16(vf, pf[qg], o_acc[d][qg], 0, 0, 0);
        }
      }
    }

    // epilogue per q-group
#pragma unroll
    for (int qg = 0; qg < 2; ++qg) {
      float l = l_part[qg];
      l += __shfl_xor(l, 16, 64);
      l += __shfl_xor(l, 32, 64);
      const float inv_l = 1.0f / l;
      const size_t orow = qkbase + (size_t)(qb * 128 + wid * 32 + qg * 16 + lm) * EMBED;
#pragma unroll
      for (int d = 0; d < 4; ++d) {
        uint2 pk;
        pk.x = pk2(o_acc[d][qg][0] * inv_l, o_acc[d][qg][1] * inv_l);
        pk.y = pk2(o_acc[d][qg][2] * inv_l, o_acc[d][qg][3] * inv_l);
        *(uint2*)&Ob[orow + d * 16 + quad * 4] = pk;
      }
    }
  }
}

// ---------------------------------------------------------------------------
// launch
// ---------------------------------------------------------------------------
extern "C" void kernel_launch(void* const* d_in, const int* in_sizes, int n_in,
                              void* d_out, int out_size, void* d_ws, size_t ws_size,
                              hipStream_t stream) {
  // setup_inputs() order: key, query, value, mask, Wq, Wk, Wv, Wo
  const float* key   = (const float*)d_in[0];
  const float* query = (const float*)d_in[1];
  const float* value = (const float*)d_in[2];
  // d_in[3] = static causal tril, handled analytically
  const float* Wq = (const float*)d_in[4];
  const float* Wk = (const float*)d_in[5];
  const float* Wv = (const float*)d_in[6];
  const float* Wo = (const float*)d_in[7];

  char* ws = (char*)d_ws;
  const size_t MB = 1024 * 1024;
  ushort_t* Xk  = (ushort_t*)(ws + 0 * MB);    // key   bf16 [4096][1024]
  ushort_t* Xq  = (ushort_t*)(ws + 8 * MB);    // query bf16
  ushort_t* Xv  = (ushort_t*)(ws + 16 * MB);   // value bf16
  ushort_t* Wqb = (ushort_t*)(ws + 24 * MB);   // pre-scaled by 0.125*log2e
  ushort_t* Wkb = (ushort_t*)(ws + 26 * MB);
  ushort_t* Wvb = (ushort_t*)(ws + 28 * MB);
  ushort_t* Wob = (ushort_t*)(ws + 30 * MB);
  ushort_t* Qp  = (ushort_t*)(ws + 32 * MB);   // projected Q (log2e-scaled)
  ushort_t* Kp  = (ushort_t*)(ws + 40 * MB);
  ushort_t* VpT = (ushort_t*)(ws + 48 * MB);   // [b][h][64][2048]
  ushort_t* Ob  = (ushort_t*)(ws + 56 * MB);   // attention out bf16

  CvtArgs ca;
  const size_t CE = 1048576;
  for (int c = 0; c < 16; ++c) ca.scale[c] = 1.0f;
  for (int c = 0; c < 4; ++c) { ca.src[c]     = key   + c * CE; ca.dst[c]     = Xk + c * CE; }
  for (int c = 0; c < 4; ++c) { ca.src[4 + c] = query + c * CE; ca.dst[4 + c] = Xq + c * CE; }
  for (int c = 0; c < 4; ++c) { ca.src[8 + c] = value + c * CE; ca.dst[8 + c] = Xv + c * CE; }
  ca.src[12] = Wq; ca.dst[12] = Wqb; ca.scale[12] = QK_SCALE;
  ca.src[13] = Wk; ca.dst[13] = Wkb;
  ca.src[14] = Wv; ca.dst[14] = Wvb;
  ca.src[15] = Wo; ca.dst[15] = Wob;
  cvt_kernel<<<8192, 256, 0, stream>>>(ca);

  QkvArgs qa;
  qa.A[0] = Xq; qa.W[0] = Wqb; qa.C[0] = (char*)Qp;
  qa.A[1] = Xk; qa.W[1] = Wkb; qa.C[1] = (char*)Kp;
  qa.A[2] = Xv; qa.W[2] = Wvb; qa.C[2] = (char*)VpT;   // z=2 writes transposed
  qkv_gemm<<<768, 256, 0, stream>>>(qa);

  attn_kernel<<<256, 256, 0, stream>>>(Qp, Kp, VpT, Ob);

  o_gemm<<<256, 256, 0, stream>>>(Ob, Wob, (float*)d_out);
}

// Round 5
// 266.219 us; speedup vs baseline: 1.1286x; 1.1286x over previous
//
#include <hip/hip_runtime.h>
#include <stdint.h>

// ---------------------------------------------------------------------------
// MHA block, round 5.
// Model (r3/r4 evidence): GEMM-shaped kernels are bound by L3 service of
// LDS-staged volume (~5.6 TB/s); FETCH stays ~unique when grids are natural
// (consecutive blocks share the large operand).  r4's %8 XCD swizzle broke
// locality (FETCH 37->112MB) -> reverted; lever is bytes-staged-per-FLOP.
// Changes:
//  * qkv: BM=256 x BN=128, BK=64, 512 thr / 8 waves, natural grid (16,8,3);
//    staged 384->288MB.  __launch_bounds__(512,4) caps VGPR at 128.
//  * attn: BQ=128 q-cols per block, KT=64 (K/V reuse actually doubled ->
//    staged 270->139MB); 512 blocks, one q-block each, qb descending (LPT);
//    natural bh order, no XCD assumptions.
//  * o_gemm: 128x128 tile (NSUB=4), natural grid (32,8); staged 192->128MB.
// ---------------------------------------------------------------------------

typedef unsigned short ushort_t;
typedef __attribute__((ext_vector_type(8))) __bf16 bf16x8;   // MFMA A/B operand
typedef __attribute__((ext_vector_type(4))) float floatx4;   // MFMA C/D operand

#define EMBED 1024
#define SEQ   2048
#define NH    16
#define DH    64
#define QK_SCALE 0.18033688011112042f   // 0.125 * log2(e)

// fp32 -> bf16 round-to-nearest-even (finite inputs)
__device__ inline ushort_t f2b(float x) {
  unsigned u = __float_as_uint(x);
  u += 0x7FFFu + ((u >> 16) & 1u);
  return (ushort_t)(u >> 16);
}

// pack bf16(a) | bf16(b)<<16 with +0x8000 round: 2 add + 1 perm
__device__ inline unsigned pk2(float a, float b) {
  unsigned ua = __float_as_uint(a) + 0x8000u;
  unsigned ub = __float_as_uint(b) + 0x8000u;
  return __builtin_amdgcn_perm(ub, ua, 0x07060302u);   // [a2,a3,b2,b3]
}

// async global->LDS, 16B/lane; LDS dest = wave-uniform base (+ lane*16 by HW)
__device__ inline void gl_lds16(const ushort_t* g, ushort_t* l) {
  __builtin_amdgcn_global_load_lds(
      (const __attribute__((address_space(1))) unsigned int*)g,
      (__attribute__((address_space(3))) unsigned int*)l, 16, 0, 0);
}

// ---------------------------------------------------------------------------
// fp32 -> bf16 bulk convert, with per-chunk scale (folds QK scale into Wq)
// ---------------------------------------------------------------------------
struct CvtArgs {
  const float* src[16];
  ushort_t*    dst[16];
  float        scale[16];
};

__global__ __launch_bounds__(256) void cvt_kernel(CvtArgs a) {
  const int chunk = blockIdx.x >> 9;
  const int off = ((blockIdx.x & 511) << 11) + (threadIdx.x << 3);
  const float sc = a.scale[chunk];
  const float4* s = (const float4*)(a.src[chunk] + off);
  float4 f0 = s[0], f1 = s[1];
  union { ushort_t u[8]; uint4 v; } o;
  o.u[0] = f2b(f0.x * sc); o.u[1] = f2b(f0.y * sc);
  o.u[2] = f2b(f0.z * sc); o.u[3] = f2b(f0.w * sc);
  o.u[4] = f2b(f1.x * sc); o.u[5] = f2b(f1.y * sc);
  o.u[6] = f2b(f1.z * sc); o.u[7] = f2b(f1.w * sc);
  *(uint4*)(a.dst[chunk] + off) = o.v;
}

// ---------------------------------------------------------------------------
// Shared epilogue: write one 16x16 C subtile from C-layout accumulator.
//   mode 0 = bf16 row-major, 1 = f32 row-major, 2 = bf16 into VpT[b][h][d][s]
// ---------------------------------------------------------------------------
__device__ inline void store_sub(char* __restrict__ Cv, const int mode,
                                 const int ldc, const int row, const int col,
                                 const floatx4& acc) {
  if (mode == 0) {
    ushort_t* C = (ushort_t*)Cv;
#pragma unroll
    for (int r = 0; r < 4; ++r)
      C[(size_t)(row + r) * ldc + col] = f2b(acc[r]);
  } else if (mode == 1) {
    float* C = (float*)Cv;
#pragma unroll
    for (int r = 0; r < 4; ++r)
      C[(size_t)(row + r) * ldc + col] = acc[r];
  } else {
    // VpT[b][h][d][s]: r -> consecutive s, one 8B store
    ushort_t* C = (ushort_t*)Cv;
    const int b = row >> 11, s = row & 2047;
    const int h = col >> 6, d = col & 63;
    uint2 pk;
    pk.x = pk2(acc[0], acc[1]);
    pk.y = pk2(acc[2], acc[3]);
    *(uint2*)&C[(size_t)((b * NH + h) * DH + d) * SEQ + s] = pk;
  }
}

// ---------------------------------------------------------------------------
// 512-thread GEMM core: C[m,n] = sum_k A[m,k]*W[n,k], K=1024 fixed.
// BM=256, BN=128, BK=64; 8 waves as 4m x 2n, each wave 64x64 (4x4 subtiles).
// Fragment-ordered LDS + global_load_lds.  48 chunks staged, 6 per wave.
// ---------------------------------------------------------------------------
__device__ inline void gemm512_core(const ushort_t* __restrict__ A,
                                    const ushort_t* __restrict__ W,
                                    char* __restrict__ Cv, const int mode,
                                    const int ldc, const int m0, const int n0) {
  __shared__ ushort_t As[32 * 512];   // 256 x 64 bf16, fragment-ordered
  __shared__ ushort_t Bs[16 * 512];   // 128 x 64
  const int tid  = threadIdx.x;
  const int lane = tid & 63;
  const int wid  = tid >> 6;          // 0..7
  const int lm   = lane & 15;
  const int quad = lane >> 4;
  const int wm   = wid >> 1;          // 0..3
  const int wn   = wid & 1;           // 0..1

  floatx4 zero = {0.f, 0.f, 0.f, 0.f};
  floatx4 acc[4][4];
#pragma unroll
  for (int i = 0; i < 4; ++i)
#pragma unroll
    for (int j = 0; j < 4; ++j) acc[i][j] = zero;

  for (int k0 = 0; k0 < EMBED; k0 += 64) {
    __syncthreads();
#pragma unroll
    for (int u = 0; u < 6; ++u) {
      const int c   = wid * 6 + u;     // 0..47, wave-uniform
      const int cb  = c & 31;          // chunk within its array
      const int sub = cb >> 1;
      const int kc  = (cb & 1) * 32 + quad * 8;
      if (c < 32)
        gl_lds16(A + (size_t)(m0 + sub * 16 + lm) * EMBED + k0 + kc, &As[cb * 512]);
      else
        gl_lds16(W + (size_t)(n0 + sub * 16 + lm) * EMBED + k0 + kc, &Bs[cb * 512]);
    }
    __syncthreads();   // vmcnt drain -> LDS visible

#pragma unroll
    for (int ks = 0; ks < 2; ++ks) {
      bf16x8 a[4], b[4];
#pragma unroll
      for (int i = 0; i < 4; ++i)
        a[i] = *(const bf16x8*)&As[((wm * 4 + i) * 2 + ks) * 512 + lane * 8];
#pragma unroll
      for (int j = 0; j < 4; ++j)
        b[j] = *(const bf16x8*)&Bs[((wn * 4 + j) * 2 + ks) * 512 + lane * 8];
#pragma unroll
      for (int i = 0; i < 4; ++i)
#pragma unroll
        for (int j = 0; j < 4; ++j)
          acc[i][j] = __builtin_amdgcn_mfma_f32_16x16x32_bf16(a[i], b[j], acc[i][j], 0, 0, 0);
    }
  }

#pragma unroll
  for (int i = 0; i < 4; ++i) {
    const int row = m0 + wm * 64 + i * 16 + quad * 4;
#pragma unroll
    for (int j = 0; j < 4; ++j)
      store_sub(Cv, mode, ldc, row, n0 + wn * 64 + j * 16 + lm, acc[i][j]);
  }
}

struct QkvArgs {
  const ushort_t* A[3];
  const ushort_t* W[3];
  char*           C[3];
};

// grid (16,8,3) natural: consecutive x share the y B-slab (the r3-verified
// locality pattern); z slowest.
__global__ __launch_bounds__(512, 4) void qkv_gemm(QkvArgs q) {
  const int z = blockIdx.z;
  gemm512_core(q.A[z], q.W[z], q.C[z], z == 2 ? 2 : 0, EMBED,
               blockIdx.x * 256, blockIdx.y * 128);
}

// ---------------------------------------------------------------------------
// 256-thread GEMM core (r3-verified), used for the O-projection.
// 128 x 128 tile, BK=64, 4 waves 2x2.
// ---------------------------------------------------------------------------
__global__ __launch_bounds__(256) void o_gemm(const ushort_t* __restrict__ A,
                                              const ushort_t* __restrict__ W,
                                              float* __restrict__ C) {
  __shared__ ushort_t As[16 * 512];   // 128 x 64, fragment-ordered
  __shared__ ushort_t Bs[16 * 512];
  const int m0 = blockIdx.x * 128, n0 = blockIdx.y * 128;
  const int tid  = threadIdx.x;
  const int lane = tid & 63;
  const int wid  = tid >> 6;
  const int lm   = lane & 15;
  const int quad = lane >> 4;

  floatx4 zero = {0.f, 0.f, 0.f, 0.f};
  floatx4 acc[4][4];
#pragma unroll
  for (int i = 0; i < 4; ++i)
#pragma unroll
    for (int j = 0; j < 4; ++j) acc[i][j] = zero;

  const int tm = (wid >> 1) * 4;
  const int tn = (wid & 1) * 4;

  for (int k0 = 0; k0 < EMBED; k0 += 64) {
    __syncthreads();
#pragma unroll
    for (int u = 0; u < 8; ++u) {
      const int c   = wid * 8 + u;     // 0..31
      const int cb  = c & 15;
      const int sub = cb >> 1;
      const int kc  = (cb & 1) * 32 + quad * 8;
      if (c < 16)
        gl_lds16(A + (size_t)(m0 + sub * 16 + lm) * EMBED + k0 + kc, &As[cb * 512]);
      else
        gl_lds16(W + (size_t)(n0 + sub * 16 + lm) * EMBED + k0 + kc, &Bs[cb * 512]);
    }
    __syncthreads();

#pragma unroll
    for (int ks = 0; ks < 2; ++ks) {
      bf16x8 a[4], b[4];
#pragma unroll
      for (int i = 0; i < 4; ++i)
        a[i] = *(const bf16x8*)&As[((tm + i) * 2 + ks) * 512 + lane * 8];
#pragma unroll
      for (int j = 0; j < 4; ++j)
        b[j] = *(const bf16x8*)&Bs[((tn + j) * 2 + ks) * 512 + lane * 8];
#pragma unroll
      for (int i = 0; i < 4; ++i)
#pragma unroll
        for (int j = 0; j < 4; ++j)
          acc[i][j] = __builtin_amdgcn_mfma_f32_16x16x32_bf16(a[i], b[j], acc[i][j], 0, 0, 0);
    }
  }

#pragma unroll
  for (int i = 0; i < 4; ++i) {
    const int row = m0 + (wid >> 1) * 64 + i * 16 + quad * 4;
#pragma unroll
    for (int j = 0; j < 4; ++j) {
      const int col = n0 + (wid & 1) * 64 + j * 16 + lm;
#pragma unroll
      for (int r = 0; r < 4; ++r)
        C[(size_t)(row + r) * EMBED + col] = acc[i][j][r];
    }
  }
}

// ---------------------------------------------------------------------------
// Causal flash attention, S^T formulation, fixed-shift softmax.
// Grid 512 x 256thr (4 waves).  Block = 128 q-cols of one (b,h); wave owns
// 32 q (2 groups of 16).  KT=64 kk per iter -> K/V staged bytes halved vs
// KT=128 at equal reuse.  qb descending in dispatch order (LPT greedy ->
// per-CU iter totals self-balance at 2 blocks/CU).
// Qs/Pw wave-private; Ks/VTs shared (2 barriers/iter).
// ---------------------------------------------------------------------------
__global__ __launch_bounds__(256) void attn_kernel(const ushort_t* __restrict__ Qp,
                                                   const ushort_t* __restrict__ Kp,
                                                   const ushort_t* __restrict__ VpT,
                                                   ushort_t* __restrict__ Ob) {
  __shared__ ushort_t Qs[16 * 512];   // 128 q x 64 d, fragment-ordered
  __shared__ ushort_t Ks[8 * 512];    // 64 kk x 64 d
  __shared__ ushort_t VTs[8 * 512];   // 64 d x 64 kk
  __shared__ ushort_t Pw[4 * 2048];   // per-wave 32 q x 64 kk
  const int L = blockIdx.x;           // 0..511
  const int qb = 15 - (L >> 5);       // descending: big blocks dispatch first
  const int bh = L & 31;
  const int h = bh & (NH - 1), b = bh >> 4;
  const int tid = threadIdx.x, lane = tid & 63, wid = tid >> 6;
  const int lm = lane & 15, quad = lane >> 4;
  const size_t qkbase = ((size_t)b * SEQ) * EMBED + h * DH;
  const size_t vtbase = ((size_t)(b * NH + h)) * DH * SEQ;
  ushort_t* pwb = &Pw[wid * 2048];

  // Q staging: chunks c = wid*4+u are wave-private (q-subtiles wid*2, wid*2+1)
#pragma unroll
  for (int u = 0; u < 4; ++u) {
    const int c = wid * 4 + u;
    gl_lds16(Qp + qkbase + (size_t)(qb * 128 + (c >> 1) * 16 + lm) * EMBED
                 + (c & 1) * 32 + quad * 8,
             &Qs[c * 512]);
  }
  asm volatile("s_waitcnt vmcnt(0)" ::: "memory");   // wave-local drain
  bf16x8 qf[2][2];   // [qg][ks]
#pragma unroll
  for (int qg = 0; qg < 2; ++qg)
#pragma unroll
    for (int ks = 0; ks < 2; ++ks)
      qf[qg][ks] = *(const bf16x8*)&Qs[((wid * 2 + qg) * 2 + ks) * 512 + lane * 8];

  float l_part[2] = {0.f, 0.f};
  floatx4 zero = {0.f, 0.f, 0.f, 0.f};
  floatx4 o_acc[4][2];
#pragma unroll
  for (int d = 0; d < 4; ++d)
#pragma unroll
    for (int qg = 0; qg < 2; ++qg) o_acc[d][qg] = zero;

  const int kt_end = 2 * qb + 1;
  for (int kt = 0; kt <= kt_end; ++kt) {
    __syncthreads();   // prior iter's Ks/VTs reads done
#pragma unroll
    for (int u = 0; u < 4; ++u) {
      const int t = wid * 4 + u;       // 0..15
      const int cb = t & 7;
      const int sub = cb >> 1;
      const int half = cb & 1;
      if (t < 8)
        gl_lds16(Kp + qkbase + (size_t)(kt * 64 + sub * 16 + lm) * EMBED
                     + half * 32 + quad * 8,
                 &Ks[cb * 512]);
      else
        gl_lds16(VpT + vtbase + (size_t)(sub * 16 + lm) * SEQ
                     + kt * 64 + half * 32 + quad * 8,
                 &VTs[cb * 512]);
    }
    __syncthreads();   // vmcnt drain -> LDS visible

    // S^T = K Q^T (log2e domain): s_acc[i][qg], i = kk-subtile 0..3
    floatx4 s_acc[4][2];
#pragma unroll
    for (int i = 0; i < 4; ++i)
#pragma unroll
      for (int qg = 0; qg < 2; ++qg) s_acc[i][qg] = zero;
#pragma unroll
    for (int ks = 0; ks < 2; ++ks)
#pragma unroll
      for (int i = 0; i < 4; ++i) {
        bf16x8 kf = *(const bf16x8*)&Ks[(i * 2 + ks) * 512 + lane * 8];
#pragma unroll
        for (int qg = 0; qg < 2; ++qg)
          s_acc[i][qg] = __builtin_amdgcn_mfma_f32_16x16x32_bf16(kf, qf[qg][ks], s_acc[i][qg], 0, 0, 0);
      }

    // exp2, diagonal mask, l accumulate, pack P^T into wave-private Pw
    const bool diag = (kt >= 2 * qb);   // uniform branch; last two iters
#pragma unroll
    for (int i = 0; i < 4; ++i) {
      const int s = i >> 1;
      const int quadB = ((i & 1) << 1) | (quad >> 1);
      const int gkk = kt * 64 + i * 16 + quad * 4;
#pragma unroll
      for (int qg = 0; qg < 2; ++qg) {
        float p[4];
#pragma unroll
        for (int r = 0; r < 4; ++r) p[r] = __builtin_amdgcn_exp2f(s_acc[i][qg][r]);
        if (diag) {
          const int gq = qb * 128 + wid * 32 + qg * 16 + lm;
#pragma unroll
          for (int r = 0; r < 4; ++r)
            if (gkk + r > gq) p[r] = 0.f;
        }
#pragma unroll
        for (int r = 0; r < 4; ++r) l_part[qg] += p[r];
        uint2 pk;
        pk.x = pk2(p[0], p[1]);
        pk.y = pk2(p[2], p[3]);
        *(uint2*)&pwb[(qg * 2 + s) * 512 + (quadB * 16 + lm) * 8 + ((quad & 1) << 2)] = pk;
      }
    }
    asm volatile("s_waitcnt lgkmcnt(0)" ::: "memory");   // wave-local RAW fence

    // O^T += V^T P^T
#pragma unroll
    for (int s = 0; s < 2; ++s) {
      bf16x8 pf[2];
#pragma unroll
      for (int qg = 0; qg < 2; ++qg)
        pf[qg] = *(const bf16x8*)&pwb[(qg * 2 + s) * 512 + lane * 8];
#pragma unroll
      for (int d = 0; d < 4; ++d) {
        bf16x8 vf = *(const bf16x8*)&VTs[(d * 2 + s) * 512 + lane * 8];
#pragma unroll
        for (int qg = 0; qg < 2; ++qg)
          o_acc[d][qg] = __builtin_amdgcn_mfma_f32_16x16x32_bf16(vf, pf[qg], o_acc[d][qg], 0, 0, 0);
      }
    }
  }

  // epilogue per q-group
#pragma unroll
  for (int qg = 0; qg < 2; ++qg) {
    float l = l_part[qg];
    l += __shfl_xor(l, 16, 64);
    l += __shfl_xor(l, 32, 64);
    const float inv_l = 1.0f / l;
    const size_t orow = qkbase + (size_t)(qb * 128 + wid * 32 + qg * 16 + lm) * EMBED;
#pragma unroll
    for (int d = 0; d < 4; ++d) {
      uint2 pk;
      pk.x = pk2(o_acc[d][qg][0] * inv_l, o_acc[d][qg][1] * inv_l);
      pk.y = pk2(o_acc[d][qg][2] * inv_l, o_acc[d][qg][3] * inv_l);
      *(uint2*)&Ob[orow + d * 16 + quad * 4] = pk;
    }
  }
}

// ---------------------------------------------------------------------------
// launch
// ---------------------------------------------------------------------------
extern "C" void kernel_launch(void* const* d_in, const int* in_sizes, int n_in,
                              void* d_out, int out_size, void* d_ws, size_t ws_size,
                              hipStream_t stream) {
  // setup_inputs() order: key, query, value, mask, Wq, Wk, Wv, Wo
  const float* key   = (const float*)d_in[0];
  const float* query = (const float*)d_in[1];
  const float* value = (const float*)d_in[2];
  // d_in[3] = static causal tril, handled analytically
  const float* Wq = (const float*)d_in[4];
  const float* Wk = (const float*)d_in[5];
  const float* Wv = (const float*)d_in[6];
  const float* Wo = (const float*)d_in[7];

  char* ws = (char*)d_ws;
  const size_t MB = 1024 * 1024;
  ushort_t* Xk  = (ushort_t*)(ws + 0 * MB);    // key   bf16 [4096][1024]
  ushort_t* Xq  = (ushort_t*)(ws + 8 * MB);    // query bf16
  ushort_t* Xv  = (ushort_t*)(ws + 16 * MB);   // value bf16
  ushort_t* Wqb = (ushort_t*)(ws + 24 * MB);   // pre-scaled by 0.125*log2e
  ushort_t* Wkb = (ushort_t*)(ws + 26 * MB);
  ushort_t* Wvb = (ushort_t*)(ws + 28 * MB);
  ushort_t* Wob = (ushort_t*)(ws + 30 * MB);
  ushort_t* Qp  = (ushort_t*)(ws + 32 * MB);   // projected Q (log2e-scaled)
  ushort_t* Kp  = (ushort_t*)(ws + 40 * MB);
  ushort_t* VpT = (ushort_t*)(ws + 48 * MB);   // [b][h][64][2048]
  ushort_t* Ob  = (ushort_t*)(ws + 56 * MB);   // attention out bf16

  CvtArgs ca;
  const size_t CE = 1048576;
  for (int c = 0; c < 16; ++c) ca.scale[c] = 1.0f;
  for (int c = 0; c < 4; ++c) { ca.src[c]     = key   + c * CE; ca.dst[c]     = Xk + c * CE; }
  for (int c = 0; c < 4; ++c) { ca.src[4 + c] = query + c * CE; ca.dst[4 + c] = Xq + c * CE; }
  for (int c = 0; c < 4; ++c) { ca.src[8 + c] = value + c * CE; ca.dst[8 + c] = Xv + c * CE; }
  ca.src[12] = Wq; ca.dst[12] = Wqb; ca.scale[12] = QK_SCALE;
  ca.src[13] = Wk; ca.dst[13] = Wkb;
  ca.src[14] = Wv; ca.dst[14] = Wvb;
  ca.src[15] = Wo; ca.dst[15] = Wob;
  cvt_kernel<<<8192, 256, 0, stream>>>(ca);

  QkvArgs qa;
  qa.A[0] = Xq; qa.W[0] = Wqb; qa.C[0] = (char*)Qp;
  qa.A[1] = Xk; qa.W[1] = Wkb; qa.C[1] = (char*)Kp;
  qa.A[2] = Xv; qa.W[2] = Wvb; qa.C[2] = (char*)VpT;   // z=2 writes transposed
  qkv_gemm<<<dim3(16, 8, 3), 512, 0, stream>>>(qa);

  attn_kernel<<<512, 256, 0, stream>>>(Qp, Kp, VpT, Ob);

  o_gemm<<<dim3(32, 8), 256, 0, stream>>>(Ob, Wob, (float*)d_out);
}

// Round 6
// 254.726 us; speedup vs baseline: 1.1796x; 1.0451x over previous
//
#include <hip/hip_runtime.h>
#include <stdint.h>

// ---------------------------------------------------------------------------
// MHA block, round 6.
// r5 post-mortem: attn no longer fetch-bound (FETCH 12MB) but back at 70us:
// (a) breadth-first pairing (k,k+256) made per-CU iters 20..48 vs 34 avg;
// (b) 2 barriers + vmcnt(0) drain per iter serialize staging and compute.
// Changes (attn only):
//  * K/V double-buffered, one barrier/iter, issue-after-barrier prefetch:
//    vmcnt(0) [cheap: loads had all of prev compute to land] -> barrier ->
//    issue next tile into other buffer -> compute current.  LDS 48->64KB,
//    still 2 blocks/CU.
//  * balance for breadth-first dispatch: L<256 -> qb=15-(L>>5),
//    L>=256 -> qb=(L>>5)-8; CU pairs (k,k+256) sum to 15 -> uniform 34.
// qkv/o_gemm/cvt unchanged from r5.
// ---------------------------------------------------------------------------

typedef unsigned short ushort_t;
typedef __attribute__((ext_vector_type(8))) __bf16 bf16x8;   // MFMA A/B operand
typedef __attribute__((ext_vector_type(4))) float floatx4;   // MFMA C/D operand

#define EMBED 1024
#define SEQ   2048
#define NH    16
#define DH    64
#define QK_SCALE 0.18033688011112042f   // 0.125 * log2(e)

// fp32 -> bf16 round-to-nearest-even (finite inputs)
__device__ inline ushort_t f2b(float x) {
  unsigned u = __float_as_uint(x);
  u += 0x7FFFu + ((u >> 16) & 1u);
  return (ushort_t)(u >> 16);
}

// pack bf16(a) | bf16(b)<<16 with +0x8000 round: 2 add + 1 perm
__device__ inline unsigned pk2(float a, float b) {
  unsigned ua = __float_as_uint(a) + 0x8000u;
  unsigned ub = __float_as_uint(b) + 0x8000u;
  return __builtin_amdgcn_perm(ub, ua, 0x07060302u);   // [a2,a3,b2,b3]
}

// async global->LDS, 16B/lane; LDS dest = wave-uniform base (+ lane*16 by HW)
__device__ inline void gl_lds16(const ushort_t* g, ushort_t* l) {
  __builtin_amdgcn_global_load_lds(
      (const __attribute__((address_space(1))) unsigned int*)g,
      (__attribute__((address_space(3))) unsigned int*)l, 16, 0, 0);
}

// ---------------------------------------------------------------------------
// fp32 -> bf16 bulk convert, with per-chunk scale (folds QK scale into Wq)
// ---------------------------------------------------------------------------
struct CvtArgs {
  const float* src[16];
  ushort_t*    dst[16];
  float        scale[16];
};

__global__ __launch_bounds__(256) void cvt_kernel(CvtArgs a) {
  const int chunk = blockIdx.x >> 9;
  const int off = ((blockIdx.x & 511) << 11) + (threadIdx.x << 3);
  const float sc = a.scale[chunk];
  const float4* s = (const float4*)(a.src[chunk] + off);
  float4 f0 = s[0], f1 = s[1];
  union { ushort_t u[8]; uint4 v; } o;
  o.u[0] = f2b(f0.x * sc); o.u[1] = f2b(f0.y * sc);
  o.u[2] = f2b(f0.z * sc); o.u[3] = f2b(f0.w * sc);
  o.u[4] = f2b(f1.x * sc); o.u[5] = f2b(f1.y * sc);
  o.u[6] = f2b(f1.z * sc); o.u[7] = f2b(f1.w * sc);
  *(uint4*)(a.dst[chunk] + off) = o.v;
}

// ---------------------------------------------------------------------------
// Shared epilogue: write one 16x16 C subtile from C-layout accumulator.
//   mode 0 = bf16 row-major, 1 = f32 row-major, 2 = bf16 into VpT[b][h][d][s]
// ---------------------------------------------------------------------------
__device__ inline void store_sub(char* __restrict__ Cv, const int mode,
                                 const int ldc, const int row, const int col,
                                 const floatx4& acc) {
  if (mode == 0) {
    ushort_t* C = (ushort_t*)Cv;
#pragma unroll
    for (int r = 0; r < 4; ++r)
      C[(size_t)(row + r) * ldc + col] = f2b(acc[r]);
  } else if (mode == 1) {
    float* C = (float*)Cv;
#pragma unroll
    for (int r = 0; r < 4; ++r)
      C[(size_t)(row + r) * ldc + col] = acc[r];
  } else {
    // VpT[b][h][d][s]: r -> consecutive s, one 8B store
    ushort_t* C = (ushort_t*)Cv;
    const int b = row >> 11, s = row & 2047;
    const int h = col >> 6, d = col & 63;
    uint2 pk;
    pk.x = pk2(acc[0], acc[1]);
    pk.y = pk2(acc[2], acc[3]);
    *(uint2*)&C[(size_t)((b * NH + h) * DH + d) * SEQ + s] = pk;
  }
}

// ---------------------------------------------------------------------------
// 512-thread GEMM core: C[m,n] = sum_k A[m,k]*W[n,k], K=1024 fixed.
// BM=256, BN=128, BK=64; 8 waves as 4m x 2n, each wave 64x64 (4x4 subtiles).
// ---------------------------------------------------------------------------
__device__ inline void gemm512_core(const ushort_t* __restrict__ A,
                                    const ushort_t* __restrict__ W,
                                    char* __restrict__ Cv, const int mode,
                                    const int ldc, const int m0, const int n0) {
  __shared__ ushort_t As[32 * 512];   // 256 x 64 bf16, fragment-ordered
  __shared__ ushort_t Bs[16 * 512];   // 128 x 64
  const int tid  = threadIdx.x;
  const int lane = tid & 63;
  const int wid  = tid >> 6;          // 0..7
  const int lm   = lane & 15;
  const int quad = lane >> 4;
  const int wm   = wid >> 1;          // 0..3
  const int wn   = wid & 1;           // 0..1

  floatx4 zero = {0.f, 0.f, 0.f, 0.f};
  floatx4 acc[4][4];
#pragma unroll
  for (int i = 0; i < 4; ++i)
#pragma unroll
    for (int j = 0; j < 4; ++j) acc[i][j] = zero;

  for (int k0 = 0; k0 < EMBED; k0 += 64) {
    __syncthreads();
#pragma unroll
    for (int u = 0; u < 6; ++u) {
      const int c   = wid * 6 + u;     // 0..47, wave-uniform
      const int cb  = c & 31;          // chunk within its array
      const int sub = cb >> 1;
      const int kc  = (cb & 1) * 32 + quad * 8;
      if (c < 32)
        gl_lds16(A + (size_t)(m0 + sub * 16 + lm) * EMBED + k0 + kc, &As[cb * 512]);
      else
        gl_lds16(W + (size_t)(n0 + sub * 16 + lm) * EMBED + k0 + kc, &Bs[cb * 512]);
    }
    __syncthreads();   // vmcnt drain -> LDS visible

#pragma unroll
    for (int ks = 0; ks < 2; ++ks) {
      bf16x8 a[4], b[4];
#pragma unroll
      for (int i = 0; i < 4; ++i)
        a[i] = *(const bf16x8*)&As[((wm * 4 + i) * 2 + ks) * 512 + lane * 8];
#pragma unroll
      for (int j = 0; j < 4; ++j)
        b[j] = *(const bf16x8*)&Bs[((wn * 4 + j) * 2 + ks) * 512 + lane * 8];
#pragma unroll
      for (int i = 0; i < 4; ++i)
#pragma unroll
        for (int j = 0; j < 4; ++j)
          acc[i][j] = __builtin_amdgcn_mfma_f32_16x16x32_bf16(a[i], b[j], acc[i][j], 0, 0, 0);
    }
  }

#pragma unroll
  for (int i = 0; i < 4; ++i) {
    const int row = m0 + wm * 64 + i * 16 + quad * 4;
#pragma unroll
    for (int j = 0; j < 4; ++j)
      store_sub(Cv, mode, ldc, row, n0 + wn * 64 + j * 16 + lm, acc[i][j]);
  }
}

struct QkvArgs {
  const ushort_t* A[3];
  const ushort_t* W[3];
  char*           C[3];
};

// grid (16,8,3) natural: consecutive x share the y B-slab
__global__ __launch_bounds__(512, 4) void qkv_gemm(QkvArgs q) {
  const int z = blockIdx.z;
  gemm512_core(q.A[z], q.W[z], q.C[z], z == 2 ? 2 : 0, EMBED,
               blockIdx.x * 256, blockIdx.y * 128);
}

// ---------------------------------------------------------------------------
// 256-thread GEMM core, O-projection.  128 x 128 tile, BK=64, 4 waves 2x2.
// ---------------------------------------------------------------------------
__global__ __launch_bounds__(256) void o_gemm(const ushort_t* __restrict__ A,
                                              const ushort_t* __restrict__ W,
                                              float* __restrict__ C) {
  __shared__ ushort_t As[16 * 512];   // 128 x 64, fragment-ordered
  __shared__ ushort_t Bs[16 * 512];
  const int m0 = blockIdx.x * 128, n0 = blockIdx.y * 128;
  const int tid  = threadIdx.x;
  const int lane = tid & 63;
  const int wid  = tid >> 6;
  const int lm   = lane & 15;
  const int quad = lane >> 4;

  floatx4 zero = {0.f, 0.f, 0.f, 0.f};
  floatx4 acc[4][4];
#pragma unroll
  for (int i = 0; i < 4; ++i)
#pragma unroll
    for (int j = 0; j < 4; ++j) acc[i][j] = zero;

  const int tm = (wid >> 1) * 4;
  const int tn = (wid & 1) * 4;

  for (int k0 = 0; k0 < EMBED; k0 += 64) {
    __syncthreads();
#pragma unroll
    for (int u = 0; u < 8; ++u) {
      const int c   = wid * 8 + u;     // 0..31
      const int cb  = c & 15;
      const int sub = cb >> 1;
      const int kc  = (cb & 1) * 32 + quad * 8;
      if (c < 16)
        gl_lds16(A + (size_t)(m0 + sub * 16 + lm) * EMBED + k0 + kc, &As[cb * 512]);
      else
        gl_lds16(W + (size_t)(n0 + sub * 16 + lm) * EMBED + k0 + kc, &Bs[cb * 512]);
    }
    __syncthreads();

#pragma unroll
    for (int ks = 0; ks < 2; ++ks) {
      bf16x8 a[4], b[4];
#pragma unroll
      for (int i = 0; i < 4; ++i)
        a[i] = *(const bf16x8*)&As[((tm + i) * 2 + ks) * 512 + lane * 8];
#pragma unroll
      for (int j = 0; j < 4; ++j)
        b[j] = *(const bf16x8*)&Bs[((tn + j) * 2 + ks) * 512 + lane * 8];
#pragma unroll
      for (int i = 0; i < 4; ++i)
#pragma unroll
        for (int j = 0; j < 4; ++j)
          acc[i][j] = __builtin_amdgcn_mfma_f32_16x16x32_bf16(a[i], b[j], acc[i][j], 0, 0, 0);
    }
  }

#pragma unroll
  for (int i = 0; i < 4; ++i) {
    const int row = m0 + (wid >> 1) * 64 + i * 16 + quad * 4;
#pragma unroll
    for (int j = 0; j < 4; ++j) {
      const int col = n0 + (wid & 1) * 64 + j * 16 + lm;
#pragma unroll
      for (int r = 0; r < 4; ++r)
        C[(size_t)(row + r) * EMBED + col] = acc[i][j][r];
    }
  }
}

// ---------------------------------------------------------------------------
// Causal flash attention, S^T formulation, fixed-shift softmax, K/V dbuf.
// Grid 512 x 256thr (4 waves).  Block = 128 q-cols of one (b,h); wave owns
// 32 q (2 groups of 16).  KT=64.  One barrier per iter; next K/V tile's
// global_load_lds issued right after the barrier, landing during compute.
// qb map pairs (k, k+256) -> qb + qb' = 15 (uniform 34 iters per CU under
// breadth-first dispatch; no worse than r5 otherwise).
// ---------------------------------------------------------------------------
__global__ __launch_bounds__(256) void attn_kernel(const ushort_t* __restrict__ Qp,
                                                   const ushort_t* __restrict__ Kp,
                                                   const ushort_t* __restrict__ VpT,
                                                   ushort_t* __restrict__ Ob) {
  __shared__ ushort_t Qs[16 * 512];      // 128 q x 64 d, fragment-ordered
  __shared__ ushort_t Ks[2][8 * 512];    // dbuf: 64 kk x 64 d
  __shared__ ushort_t VTs[2][8 * 512];   // dbuf: 64 d x 64 kk
  __shared__ ushort_t Pw[4 * 2048];      // per-wave 32 q x 64 kk
  const int L = blockIdx.x;              // 0..511
  const int qb = (L < 256) ? (15 - (L >> 5)) : ((L >> 5) - 8);
  const int bh = L & 31;
  const int h = bh & (NH - 1), b = bh >> 4;
  const int tid = threadIdx.x, lane = tid & 63, wid = tid >> 6;
  const int lm = lane & 15, quad = lane >> 4;
  const size_t qkbase = ((size_t)b * SEQ) * EMBED + h * DH;
  const size_t vtbase = ((size_t)(b * NH + h)) * DH * SEQ;
  ushort_t* pwb = &Pw[wid * 2048];

  // per-wave staging geometry for K/VT: 4 chunks, t = wid*4+u
  // t<8 -> Ks chunk t, else VTs chunk t-8
  // Q staging: chunks c = wid*4+u are wave-private (q-subtiles wid*2, wid*2+1)
#pragma unroll
  for (int u = 0; u < 4; ++u) {
    const int c = wid * 4 + u;
    gl_lds16(Qp + qkbase + (size_t)(qb * 128 + (c >> 1) * 16 + lm) * EMBED
                 + (c & 1) * 32 + quad * 8,
             &Qs[c * 512]);
  }
  // issue K/V for kt=0 into buf 0 (behind the Q loads)
#pragma unroll
  for (int u = 0; u < 4; ++u) {
    const int t = wid * 4 + u;
    const int cb = t & 7, sub = cb >> 1, half = cb & 1;
    if (t < 8)
      gl_lds16(Kp + qkbase + (size_t)(sub * 16 + lm) * EMBED + half * 32 + quad * 8,
               &Ks[0][cb * 512]);
    else
      gl_lds16(VpT + vtbase + (size_t)(sub * 16 + lm) * SEQ + half * 32 + quad * 8,
               &VTs[0][cb * 512]);
  }
  asm volatile("s_waitcnt vmcnt(4)" ::: "memory");   // my Q chunks landed
  bf16x8 qf[2][2];   // [qg][ks]
#pragma unroll
  for (int qg = 0; qg < 2; ++qg)
#pragma unroll
    for (int ks = 0; ks < 2; ++ks)
      qf[qg][ks] = *(const bf16x8*)&Qs[((wid * 2 + qg) * 2 + ks) * 512 + lane * 8];

  float l_part[2] = {0.f, 0.f};
  floatx4 zero = {0.f, 0.f, 0.f, 0.f};
  floatx4 o_acc[4][2];
#pragma unroll
  for (int d = 0; d < 4; ++d)
#pragma unroll
    for (int qg = 0; qg < 2; ++qg) o_acc[d][qg] = zero;

  const int kt_end = 2 * qb + 1;
  for (int kt = 0; kt <= kt_end; ++kt) {
    const int cur = kt & 1;
    // my K/V[cur] loads (issued last iter / preamble) have landed by now
    asm volatile("s_waitcnt vmcnt(0)" ::: "memory");
    __syncthreads();   // all waves' cur loads landed; all done reading buf cur^1
    if (kt < kt_end) {
      const int kn = kt + 1;
#pragma unroll
      for (int u = 0; u < 4; ++u) {
        const int t = wid * 4 + u;
        const int cb = t & 7, sub = cb >> 1, half = cb & 1;
        if (t < 8)
          gl_lds16(Kp + qkbase + (size_t)(kn * 64 + sub * 16 + lm) * EMBED
                       + half * 32 + quad * 8,
                   &Ks[cur ^ 1][cb * 512]);
        else
          gl_lds16(VpT + vtbase + (size_t)(sub * 16 + lm) * SEQ
                       + kn * 64 + half * 32 + quad * 8,
                   &VTs[cur ^ 1][cb * 512]);
      }
    }

    // S^T = K Q^T (log2e domain): s_acc[i][qg], i = kk-subtile 0..3
    floatx4 s_acc[4][2];
#pragma unroll
    for (int i = 0; i < 4; ++i)
#pragma unroll
      for (int qg = 0; qg < 2; ++qg) s_acc[i][qg] = zero;
#pragma unroll
    for (int ks = 0; ks < 2; ++ks)
#pragma unroll
      for (int i = 0; i < 4; ++i) {
        bf16x8 kf = *(const bf16x8*)&Ks[cur][(i * 2 + ks) * 512 + lane * 8];
#pragma unroll
        for (int qg = 0; qg < 2; ++qg)
          s_acc[i][qg] = __builtin_amdgcn_mfma_f32_16x16x32_bf16(kf, qf[qg][ks], s_acc[i][qg], 0, 0, 0);
      }

    // exp2, diagonal mask, l accumulate, pack P^T into wave-private Pw
    const bool diag = (kt >= 2 * qb);   // uniform branch; last two iters
#pragma unroll
    for (int i = 0; i < 4; ++i) {
      const int s = i >> 1;
      const int quadB = ((i & 1) << 1) | (quad >> 1);
      const int gkk = kt * 64 + i * 16 + quad * 4;
#pragma unroll
      for (int qg = 0; qg < 2; ++qg) {
        float p[4];
#pragma unroll
        for (int r = 0; r < 4; ++r) p[r] = __builtin_amdgcn_exp2f(s_acc[i][qg][r]);
        if (diag) {
          const int gq = qb * 128 + wid * 32 + qg * 16 + lm;
#pragma unroll
          for (int r = 0; r < 4; ++r)
            if (gkk + r > gq) p[r] = 0.f;
        }
#pragma unroll
        for (int r = 0; r < 4; ++r) l_part[qg] += p[r];
        uint2 pk;
        pk.x = pk2(p[0], p[1]);
        pk.y = pk2(p[2], p[3]);
        *(uint2*)&pwb[(qg * 2 + s) * 512 + (quadB * 16 + lm) * 8 + ((quad & 1) << 2)] = pk;
      }
    }
    asm volatile("s_waitcnt lgkmcnt(0)" ::: "memory");   // wave-local RAW fence

    // O^T += V^T P^T
#pragma unroll
    for (int s = 0; s < 2; ++s) {
      bf16x8 pf[2];
#pragma unroll
      for (int qg = 0; qg < 2; ++qg)
        pf[qg] = *(const bf16x8*)&pwb[(qg * 2 + s) * 512 + lane * 8];
#pragma unroll
      for (int d = 0; d < 4; ++d) {
        bf16x8 vf = *(const bf16x8*)&VTs[cur][(d * 2 + s) * 512 + lane * 8];
#pragma unroll
        for (int qg = 0; qg < 2; ++qg)
          o_acc[d][qg] = __builtin_amdgcn_mfma_f32_16x16x32_bf16(vf, pf[qg], o_acc[d][qg], 0, 0, 0);
      }
    }
  }

  // epilogue per q-group
#pragma unroll
  for (int qg = 0; qg < 2; ++qg) {
    float l = l_part[qg];
    l += __shfl_xor(l, 16, 64);
    l += __shfl_xor(l, 32, 64);
    const float inv_l = 1.0f / l;
    const size_t orow = qkbase + (size_t)(qb * 128 + wid * 32 + qg * 16 + lm) * EMBED;
#pragma unroll
    for (int d = 0; d < 4; ++d) {
      uint2 pk;
      pk.x = pk2(o_acc[d][qg][0] * inv_l, o_acc[d][qg][1] * inv_l);
      pk.y = pk2(o_acc[d][qg][2] * inv_l, o_acc[d][qg][3] * inv_l);
      *(uint2*)&Ob[orow + d * 16 + quad * 4] = pk;
    }
  }
}

// ---------------------------------------------------------------------------
// launch
// ---------------------------------------------------------------------------
extern "C" void kernel_launch(void* const* d_in, const int* in_sizes, int n_in,
                              void* d_out, int out_size, void* d_ws, size_t ws_size,
                              hipStream_t stream) {
  // setup_inputs() order: key, query, value, mask, Wq, Wk, Wv, Wo
  const float* key   = (const float*)d_in[0];
  const float* query = (const float*)d_in[1];
  const float* value = (const float*)d_in[2];
  // d_in[3] = static causal tril, handled analytically
  const float* Wq = (const float*)d_in[4];
  const float* Wk = (const float*)d_in[5];
  const float* Wv = (const float*)d_in[6];
  const float* Wo = (const float*)d_in[7];

  char* ws = (char*)d_ws;
  const size_t MB = 1024 * 1024;
  ushort_t* Xk  = (ushort_t*)(ws + 0 * MB);    // key   bf16 [4096][1024]
  ushort_t* Xq  = (ushort_t*)(ws + 8 * MB);    // query bf16
  ushort_t* Xv  = (ushort_t*)(ws + 16 * MB);   // value bf16
  ushort_t* Wqb = (ushort_t*)(ws + 24 * MB);   // pre-scaled by 0.125*log2e
  ushort_t* Wkb = (ushort_t*)(ws + 26 * MB);
  ushort_t* Wvb = (ushort_t*)(ws + 28 * MB);
  ushort_t* Wob = (ushort_t*)(ws + 30 * MB);
  ushort_t* Qp  = (ushort_t*)(ws + 32 * MB);   // projected Q (log2e-scaled)
  ushort_t* Kp  = (ushort_t*)(ws + 40 * MB);
  ushort_t* VpT = (ushort_t*)(ws + 48 * MB);   // [b][h][64][2048]
  ushort_t* Ob  = (ushort_t*)(ws + 56 * MB);   // attention out bf16

  CvtArgs ca;
  const size_t CE = 1048576;
  for (int c = 0; c < 16; ++c) ca.scale[c] = 1.0f;
  for (int c = 0; c < 4; ++c) { ca.src[c]     = key   + c * CE; ca.dst[c]     = Xk + c * CE; }
  for (int c = 0; c < 4; ++c) { ca.src[4 + c] = query + c * CE; ca.dst[4 + c] = Xq + c * CE; }
  for (int c = 0; c < 4; ++c) { ca.src[8 + c] = value + c * CE; ca.dst[8 + c] = Xv + c * CE; }
  ca.src[12] = Wq; ca.dst[12] = Wqb; ca.scale[12] = QK_SCALE;
  ca.src[13] = Wk; ca.dst[13] = Wkb;
  ca.src[14] = Wv; ca.dst[14] = Wvb;
  ca.src[15] = Wo; ca.dst[15] = Wob;
  cvt_kernel<<<8192, 256, 0, stream>>>(ca);

  QkvArgs qa;
  qa.A[0] = Xq; qa.W[0] = Wqb; qa.C[0] = (char*)Qp;
  qa.A[1] = Xk; qa.W[1] = Wkb; qa.C[1] = (char*)Kp;
  qa.A[2] = Xv; qa.W[2] = Wvb; qa.C[2] = (char*)VpT;   // z=2 writes transposed
  qkv_gemm<<<dim3(16, 8, 3), 512, 0, stream>>>(qa);

  attn_kernel<<<512, 256, 0, stream>>>(Qp, Kp, VpT, Ob);

  o_gemm<<<dim3(32, 8), 256, 0, stream>>>(Ob, Wob, (float*)d_out);
}